// Round 2
// baseline (134.679 us; speedup 1.0000x reference)
//
#include <hip/hip_runtime.h>
#include <stdint.h>

#pragma clang fp contract(off)

#define BS 32
#define NMAX 64
#define A_TOT 8400
#define NC 80

// =====================  Kernel A: per-(b,g) candidate selection  =============
// For each valid gt: find top-9 nearest anchors per level (5x5 analytic window),
// compute IoU at the 27 candidates, threshold = mean + std(ddof=1), then
// scatter positives (IoU>thr && center-inside-gt) to per-anchor atomics.

template<int N, int S, int START, int C0>
__device__ __forceinline__ void do_level(
    float gcx, float gcy,
    float x1, float y1, float x2, float y2, float area_g,
    int (&aidx)[27], float (&ov)[27], float (&acxA)[27], float (&acyA)[27])
{
  unsigned long long kk[9];
#pragma unroll
  for (int i = 0; i < 9; ++i) kk[i] = ~0ULL;
  const float s = (float)S;
  int j0 = (int)floorf(gcx / s);
  int i0 = (int)floorf(gcy / s);
  int jlo = min(max(j0 - 2, 0), N - 5);
  int ilo = min(max(i0 - 2, 0), N - 5);
#pragma unroll
  for (int di = 0; di < 5; ++di) {
    int ii = ilo + di;
    float ay = ((float)ii + 0.5f) * s;
    float dy = gcy - ay;
    float dy2 = dy * dy;
#pragma unroll
    for (int dj = 0; dj < 5; ++dj) {
      int jj = jlo + dj;
      float ax = ((float)jj + 0.5f) * s;
      float dx = gcx - ax;
      float d = sqrtf(dx * dx + dy2);           // matches ref op order (x^2 then +y^2)
      unsigned long long key =
          ((unsigned long long)__float_as_uint(d) << 32) |
          (unsigned int)(START + ii * N + jj);  // (dist, idx) lexicographic => top_k tie rule
      if (key < kk[8]) {
        kk[8] = key;
#pragma unroll
        for (int t = 8; t > 0; --t) {
          unsigned long long lo = kk[t], hi = kk[t - 1];
          if (lo < hi) { kk[t] = hi; kk[t - 1] = lo; }
        }
      }
    }
  }
#pragma unroll
  for (int t = 0; t < 9; ++t) {
    int a = (int)(kk[t] & 0xffffffffULL);
    int loc = a - START;
    int ii = loc / N;
    int jj = loc - ii * N;
    float cx = ((float)jj + 0.5f) * s;          // exact: integers representable in f32
    float cy = ((float)ii + 0.5f) * s;
    const float h = 2.5f * (float)S;
    float ax1 = cx - h, ay1 = cy - h, ax2 = cx + h, ay2 = cy + h;
    float iw = fminf(x2, ax2) - fmaxf(x1, ax1); iw = fmaxf(iw, 0.f);
    float ih = fminf(y2, ay2) - fmaxf(y1, ay1); ih = fmaxf(ih, 0.f);
    float inter = iw * ih;
    float area_a = fmaxf(ax2 - ax1, 0.f) * fmaxf(ay2 - ay1, 0.f);
    float uni = fmaxf(area_g + area_a - inter, 1e-6f);
    ov[C0 + t] = inter / uni;
    aidx[C0 + t] = a;
    acxA[C0 + t] = cx;
    acyA[C0 + t] = cy;
  }
}

__global__ __launch_bounds__(256) void atss_assign_k(
    const float* __restrict__ gt_bboxes,
    const float* __restrict__ mask_gt,
    int* __restrict__ cnt, int* __restrict__ ming)
{
  int t = blockIdx.x * 256 + threadIdx.x;
  if (t >= BS * NMAX) return;
  if (!(mask_gt[t] > 0.0f)) return;   // invalid gt => is_in_candidate all 0 => no positives
  int b = t >> 6;
  int g = t & 63;
  const float* gb = gt_bboxes + (size_t)t * 4;
  float x1 = gb[0], y1 = gb[1], x2 = gb[2], y2 = gb[3];
  float gcx = (x1 + x2) * 0.5f;
  float gcy = (y1 + y2) * 0.5f;
  float area_g = fmaxf(x2 - x1, 0.f) * fmaxf(y2 - y1, 0.f);

  int aidx[27];
  float ov[27], acxA[27], acyA[27];
  do_level<80,  8,    0,  0>(gcx, gcy, x1, y1, x2, y2, area_g, aidx, ov, acxA, acyA);
  do_level<40, 16, 6400,  9>(gcx, gcy, x1, y1, x2, y2, area_g, aidx, ov, acxA, acyA);
  do_level<20, 32, 8000, 18>(gcx, gcy, x1, y1, x2, y2, area_g, aidx, ov, acxA, acyA);

  float sum = 0.f;
#pragma unroll
  for (int c = 0; c < 27; ++c) sum += ov[c];
  float mean = sum / 27.f;
  float ss = 0.f;
#pragma unroll
  for (int c = 0; c < 27; ++c) { float d = ov[c] - mean; ss += d * d; }
  float thr = mean + sqrtf(ss / 26.f);          // std ddof=1

#pragma unroll
  for (int c = 0; c < 27; ++c) {
    if (ov[c] > thr) {
      float m = fminf(fminf(acxA[c] - x1, acyA[c] - y1),
                      fminf(x2 - acxA[c], y2 - acyA[c]));
      if (m > 1e-9f) {                          // strictly inside gt (EPS_GT)
        int idx = b * A_TOT + aidx[c];
        atomicAdd(&cnt[idx], 1);
        atomicMin(&ming[idx], g);
      }
    }
  }
}

// =====================  Kernel B: per-(b,a) finalize + outputs  ==============

__global__ __launch_bounds__(256) void atss_finalize_k(
    const float* __restrict__ anc,
    const int* __restrict__ gt_labels,
    const float* __restrict__ gt_bboxes,
    const float* __restrict__ pd_bboxes,
    const int* __restrict__ cnt,
    const int* __restrict__ ming,
    float* __restrict__ out)
{
  __shared__ float s_gt[NMAX * 4];
  __shared__ int   s_lab[NMAX];
  __shared__ int   s_alab[256];
  __shared__ float s_as[256];

  const int b   = blockIdx.y;
  const int a0  = blockIdx.x * 256;
  const int tid = threadIdx.x;

  s_gt[tid] = gt_bboxes[(size_t)b * NMAX * 4 + tid];   // 256 == NMAX*4
  if (tid < NMAX) s_lab[tid] = gt_labels[b * NMAX + tid];
  __syncthreads();

  const int a = a0 + tid;
  int lab = NC; float sc = 0.f; int gsel = 0; int fg = 0;

  if (a < A_TOT) {
    const int ia = b * A_TOT + a;
    const int c = cnt[ia];
    if (c == 1) { gsel = ming[ia]; fg = 1; }
    else if (c > 1) {
      // multi-assigned: argmax over ALL 64 gts of IoU(gt, anchor), first-max tie rule
      const float* ab = anc + (size_t)a * 4;
      float ax1 = ab[0], ay1 = ab[1], ax2 = ab[2], ay2 = ab[3];
      float area_a = fmaxf(ax2 - ax1, 0.f) * fmaxf(ay2 - ay1, 0.f);
      float best = -1.f; int bg = 0;
      for (int gg = 0; gg < NMAX; ++gg) {
        float x1 = s_gt[gg * 4 + 0], y1 = s_gt[gg * 4 + 1];
        float x2 = s_gt[gg * 4 + 2], y2 = s_gt[gg * 4 + 3];
        float iw = fminf(x2, ax2) - fmaxf(x1, ax1); iw = fmaxf(iw, 0.f);
        float ih = fminf(y2, ay2) - fmaxf(y1, ay1); ih = fmaxf(ih, 0.f);
        float inter = iw * ih;
        float ag = fmaxf(x2 - x1, 0.f) * fmaxf(y2 - y1, 0.f);
        float uni = fmaxf(ag + area_a - inter, 1e-6f);
        float iou = inter / uni;
        if (iou > best) { best = iou; bg = gg; }
      }
      gsel = bg; fg = 1;
    }

    if (fg) {
      lab = s_lab[gsel];
      // score scalar = IoU(assigned gt, pd box)  (mask_pos one-hot => max over g)
      float x1 = s_gt[gsel * 4 + 0], y1 = s_gt[gsel * 4 + 1];
      float x2 = s_gt[gsel * 4 + 2], y2 = s_gt[gsel * 4 + 3];
      const float4 pb = *(const float4*)(pd_bboxes + (size_t)ia * 4);
      float iw = fminf(x2, pb.z) - fmaxf(x1, pb.x); iw = fmaxf(iw, 0.f);
      float ih = fminf(y2, pb.w) - fmaxf(y1, pb.y); ih = fmaxf(ih, 0.f);
      float inter = iw * ih;
      float ag = fmaxf(x2 - x1, 0.f) * fmaxf(y2 - y1, 0.f);
      float ap = fmaxf(pb.z - pb.x, 0.f) * fmaxf(pb.w - pb.y, 0.f);
      sc = inter / (ag + ap - inter + 1e-9f);
    }

    // labels (float32), bboxes (gt of argmax; g=0 for background — ref does this), fg
    out[ia] = (float)lab;
    float4 bb = { s_gt[gsel*4+0], s_gt[gsel*4+1], s_gt[gsel*4+2], s_gt[gsel*4+3] };
    *(float4*)(out + (size_t)BS * A_TOT + (size_t)ia * 4) = bb;
    out[(size_t)BS * A_TOT * 85 + ia] = fg ? 1.0f : 0.0f;
  }

  s_alab[tid] = lab;
  s_as[tid]   = sc;
  __syncthreads();

  // scores: one-hot(label)[:80] * sc, written cooperatively & coalesced (float4)
  const int na = min(256, A_TOT - a0);
  float* outS = out + (size_t)BS * A_TOT * 5 + ((size_t)b * A_TOT + a0) * NC;
  const int nv4 = na * (NC / 4);
  for (int i = tid; i < nv4; i += 256) {
    int al = i / (NC / 4);
    int c4 = (i - al * (NC / 4)) * 4;
    int L  = s_alab[al];
    float s = s_as[al];
    float4 v;
    v.x = (L == c4 + 0) ? s : 0.f;
    v.y = (L == c4 + 1) ? s : 0.f;
    v.z = (L == c4 + 2) ? s : 0.f;
    v.w = (L == c4 + 3) ? s : 0.f;
    ((float4*)outS)[i] = v;
  }
}

// =============================  launcher  ====================================

extern "C" void kernel_launch(void* const* d_in, const int* in_sizes, int n_in,
                              void* d_out, int out_size, void* d_ws, size_t ws_size,
                              hipStream_t stream) {
  const float* anc       = (const float*)d_in[0];
  // d_in[1] = n_level_bboxes (static: 6400/1600/400) — unused
  const int*   gt_labels = (const int*)  d_in[2];
  const float* gt_bboxes = (const float*)d_in[3];
  const float* mask_gt   = (const float*)d_in[4];
  const float* pd_bboxes = (const float*)d_in[5];
  float* out = (float*)d_out;

  int* cnt  = (int*)d_ws;
  int* ming = cnt + BS * A_TOT;

  hipMemsetAsync(cnt,  0,    BS * A_TOT * sizeof(int), stream);
  hipMemsetAsync(ming, 0x7f, BS * A_TOT * sizeof(int), stream);

  atss_assign_k<<<dim3((BS * NMAX + 255) / 256), 256, 0, stream>>>(
      gt_bboxes, mask_gt, cnt, ming);

  atss_finalize_k<<<dim3((A_TOT + 255) / 256, BS), 256, 0, stream>>>(
      anc, gt_labels, gt_bboxes, pd_bboxes, cnt, ming, out);
}